// Round 6
// baseline (27805.212 us; speedup 1.0000x reference)
//
#include <hip/hip_runtime.h>
#include <math.h>

// Problem constants: B=128, L=512, D_IN=512, D_H=1024, D_OUT=256
#define B_   128
#define L_   512
#define DIN  512
#define DH   1024
#define DOUT 256

#define NBLK 256
#define NTHR 512

typedef float f32x4 __attribute__((ext_vector_type(4)));

__device__ __forceinline__ float hload(const float* p) {
  return __hip_atomic_load(p, __ATOMIC_RELAXED, __HIP_MEMORY_SCOPE_AGENT);
}
__device__ __forceinline__ void hstore(float* p, float v) {
  __hip_atomic_store(p, v, __ATOMIC_RELAXED, __HIP_MEMORY_SCOPE_AGENT);
}

// Persistent fused RNN.
// Grid 256 x 512, 128 KB LDS -> exactly 1 block/CU, all co-resident.
// Block: m-tile = (bid&7)*16 rows, n-tile = (bid>>3)*32 cols.
// Thread: cg = lane&7 (cols cg*4..+3), kssub = lane>>3, ks = wavei*8+kssub (64 k-slices).
// Step l: h_new = tanh(X_l W_in1^T + (l>=2 ? h W_rec1^T : 0) + b_in1).
// Register plan (~212 VGPR): wrecT 64 + winT 32 + accv 64 + hreg 32 (transient) + addr.
// amdgpu_waves_per_eu(2,2) pins the budget at 256 VGPR/wave (512-reg file / 2 waves)
// so the compiler cannot shrink to 128 and spill (round-5 failure: 1 GB scratch stores).
__global__ __attribute__((amdgpu_flat_work_group_size(NTHR, NTHR),
                          amdgpu_waves_per_eu(2, 2))) void rnn_persist(
    const float* __restrict__ X, const float* __restrict__ W_in1,
    const float* __restrict__ b_in1, const float* __restrict__ W_rec1,
    const float* __restrict__ W_out, const float* __restrict__ b_out,
    float* __restrict__ hA, float* __restrict__ hB,
    unsigned* __restrict__ bar, float* __restrict__ Y) {
  __shared__ __align__(16) float Hs[16 * 1024];  // 64 KB, XOR-swizzled cols
  __shared__ __align__(16) float Xs[16 * 512];   // 32 KB, XOR-swizzled cols
  __shared__ __align__(16) float Red[16 * 512];  // 32 KB [prt][m*32+n]

  const int tid   = (int)threadIdx.x;
  const int bid   = (int)blockIdx.x;
  const int m0    = (bid & 7) * 16;
  const int n0    = (bid >> 3) * 32;
  const int lane  = tid & 63;
  const int wavei = tid >> 6;
  const int cg    = lane & 7;
  const int kssub = lane >> 3;
  const int ks    = wavei * 8 + kssub;

  // ---- register-resident weight slices, TRANSPOSED: [k][nj] as f32x4 ----
  f32x4 wrecT[16];  // wrecT[k][nj] = W_rec1[n0+cg*4+nj][ks*16+k]
  f32x4 winT[8];    // winT[k][nj]  = W_in1 [n0+cg*4+nj][ks*8+k]
#pragma unroll
  for (int k = 0; k < 16; ++k) {
#pragma unroll
    for (int nj = 0; nj < 4; ++nj)
      wrecT[k][nj] = W_rec1[(size_t)(n0 + cg * 4 + nj) * DH + ks * 16 + k];
  }
#pragma unroll
  for (int k = 0; k < 8; ++k) {
#pragma unroll
    for (int nj = 0; nj < 4; ++nj)
      winT[k][nj] = W_in1[(size_t)(n0 + cg * 4 + nj) * DIN + ks * 8 + k];
  }
  // swizzled LDS column offsets (bank-conflict-free broadcast reads)
  const int swz = (ks & 7) << 2;
  const int xq0 = (ks * 8) ^ swz;
  const int xq1 = (ks * 8 + 4) ^ swz;
  int rp[4];
#pragma unroll
  for (int j4 = 0; j4 < 4; ++j4) rp[j4] = (ks * 16 + j4 * 4) ^ swz;

  const int mo = tid >> 5, no = tid & 31;   // this thread's finalized output
  const float bi = b_in1[n0 + no];
  const int prt = wavei * 2 + (kssub >> 2); // 16 reduction partials

  unsigned phase = 0;
#pragma unroll 1
  for (int l = 1; l < L_; ++l) {
    const float* hp = (l & 1) ? hB : hA;
    float* hn       = (l & 1) ? hA : hB;

    // issue coherent h loads first; compiler defers the wait to first use
    // (the Hs publish after proj), so latency hides under X stage + proj
    float hreg[32];
    if (l > 1) {
      const float* hsrc = hp + (size_t)m0 * DH;  // this block's 16 rows (64 KB)
#pragma unroll
      for (int i = 0; i < 32; ++i) hreg[i] = hload(hsrc + tid + i * NTHR);
    }
    // stage X[:, l, :] tile: 8192 floats = 512 thr x 4 x f32x4, swizzled cols
#pragma unroll
    for (int p = 0; p < 4; ++p) {
      const int e = tid * 4 + p * 2048;
      const int m = e >> 9, k = e & 511;
      const f32x4 v = *(const f32x4*)&X[((size_t)(m0 + m) * L_ + l) * DIN + k];
      *(f32x4*)&Xs[m * 512 + (k ^ (((k >> 3) & 7) << 2))] = v;
    }
    __syncthreads();

    // ---- proj partials: accv[m][nj] ----
    f32x4 accv[16];
#pragma unroll
    for (int m = 0; m < 16; ++m) {
      const f32x4 a = *(const f32x4*)&Xs[m * 512 + xq0];
      const f32x4 b = *(const f32x4*)&Xs[m * 512 + xq1];
      f32x4 s = a[0] * winT[0];
      s += a[1] * winT[1]; s += a[2] * winT[2]; s += a[3] * winT[3];
      s += b[0] * winT[4]; s += b[1] * winT[5];
      s += b[2] * winT[6]; s += b[3] * winT[7];
      accv[m] = s;
    }

    if (l > 1) {
      // publish h to LDS (swizzled scatter), then recurrent partials
#pragma unroll
      for (int i = 0; i < 32; ++i) {
        const int idx = tid + i * NTHR;
        const int row = idx >> 10, col = idx & 1023;
        Hs[row * 1024 + (col ^ (((col >> 4) & 7) << 2))] = hreg[i];
      }
      __syncthreads();
#pragma unroll
      for (int m = 0; m < 16; ++m) {
        f32x4 s = accv[m];
#pragma unroll
        for (int j4 = 0; j4 < 4; ++j4) {
          const f32x4 h4 = *(const f32x4*)&Hs[m * 1024 + rp[j4]];
          s += h4[0] * wrecT[j4 * 4 + 0];
          s += h4[1] * wrecT[j4 * 4 + 1];
          s += h4[2] * wrecT[j4 * 4 + 2];
          s += h4[3] * wrecT[j4 * 4 + 3];
        }
        accv[m] = s;
      }
    }

    // ---- reduce: in-wave butterfly over kssub bits 0,1; Red for the rest ----
#pragma unroll
    for (int m = 0; m < 16; ++m) {
#pragma unroll
      for (int c = 0; c < 4; ++c) {
        float v = accv[m][c];
        v += __shfl_xor(v, 8);
        v += __shfl_xor(v, 16);
        accv[m][c] = v;
      }
    }
    if ((kssub & 3) == 0) {
#pragma unroll
      for (int m = 0; m < 16; ++m)
        *(f32x4*)&Red[(prt * 16 + m) * 32 + cg * 4] = accv[m];
    }
    __syncthreads();

    // ---- finalize 1 output/thread: sum 16 partials, bias, tanh, coherent store ----
    {
      float s = 0.f;
#pragma unroll
      for (int p2 = 0; p2 < 16; ++p2) s += Red[(p2 * 16 + mo) * 32 + no];
      hstore(hn + (size_t)(m0 + mo) * DH + n0 + no, tanhf(s + bi));
    }
    // ---- per-m-group barrier (32 blocks with this bid&7) ----
    __threadfence();
    __syncthreads();
    ++phase;
    if (tid == 0) {
      unsigned* ctr = bar + (size_t)(bid & 7) * 32;  // 128 B apart
      __hip_atomic_fetch_add(ctr, 1u, __ATOMIC_ACQ_REL, __HIP_MEMORY_SCOPE_AGENT);
      const unsigned tgt = phase * 32u;
      while (__hip_atomic_load(ctr, __ATOMIC_ACQUIRE, __HIP_MEMORY_SCOPE_AGENT) < tgt)
        __builtin_amdgcn_s_sleep(1);
    }
    __syncthreads();
  }

  // ---- output layer: Y = tanh(h_final @ W_out^T + b_out); h_final = hA ----
  if (bid < 64) {
    const int n0o = (bid >> 3) * 32;
    f32x4 woT[16];
#pragma unroll
    for (int k = 0; k < 16; ++k) {
#pragma unroll
      for (int nj = 0; nj < 4; ++nj)
        woT[k][nj] = W_out[(size_t)(n0o + cg * 4 + nj) * DH + ks * 16 + k];
    }
    const float bo = b_out[n0o + no];
    const float* hsrc = hA + (size_t)m0 * DH;
    float hreg[32];
#pragma unroll
    for (int i = 0; i < 32; ++i) hreg[i] = hload(hsrc + tid + i * NTHR);
#pragma unroll
    for (int i = 0; i < 32; ++i) {
      const int idx = tid + i * NTHR;
      const int row = idx >> 10, col = idx & 1023;
      Hs[row * 1024 + (col ^ (((col >> 4) & 7) << 2))] = hreg[i];
    }
    __syncthreads();
    f32x4 accv[16];
#pragma unroll
    for (int m = 0; m < 16; ++m) {
      f32x4 s = {0.f, 0.f, 0.f, 0.f};
#pragma unroll
      for (int j4 = 0; j4 < 4; ++j4) {
        const f32x4 h4 = *(const f32x4*)&Hs[m * 1024 + rp[j4]];
        s += h4[0] * woT[j4 * 4 + 0];
        s += h4[1] * woT[j4 * 4 + 1];
        s += h4[2] * woT[j4 * 4 + 2];
        s += h4[3] * woT[j4 * 4 + 3];
      }
      accv[m] = s;
    }
#pragma unroll
    for (int m = 0; m < 16; ++m) {
#pragma unroll
      for (int c = 0; c < 4; ++c) {
        float v = accv[m][c];
        v += __shfl_xor(v, 8);
        v += __shfl_xor(v, 16);
        accv[m][c] = v;
      }
    }
    if ((kssub & 3) == 0) {
#pragma unroll
      for (int m = 0; m < 16; ++m)
        *(f32x4*)&Red[(prt * 16 + m) * 32 + cg * 4] = accv[m];
    }
    __syncthreads();
    float s = 0.f;
#pragma unroll
    for (int p2 = 0; p2 < 16; ++p2) s += Red[(p2 * 16 + mo) * 32 + no];
    Y[(size_t)(m0 + mo) * DOUT + n0o + no] = tanhf(s + bo);
  }
}

extern "C" void kernel_launch(void* const* d_in, const int* in_sizes, int n_in,
                              void* d_out, int out_size, void* d_ws, size_t ws_size,
                              hipStream_t stream) {
  const float* X      = (const float*)d_in[0];
  const float* W_in1  = (const float*)d_in[1];
  const float* b_in1  = (const float*)d_in[2];
  const float* W_rec1 = (const float*)d_in[3];
  // d_in[4..6] = W_in2/b_in2/W_rec2 : dead code w.r.t. Y
  const float* W_out  = (const float*)d_in[7];
  const float* b_out  = (const float*)d_in[8];
  float* out = (float*)d_out;

  // ws layout: [0,4096): 8 group-barrier counters (128 B apart); then hA, hB
  unsigned* bar = (unsigned*)d_ws;
  float* hA = (float*)((char*)d_ws + 4096);
  float* hB = hA + (size_t)B_ * DH;

  hipMemsetAsync(d_ws, 0, 4096, stream);  // reset barriers each launch (replay-safe)
  rnn_persist<<<NBLK, NTHR, 0, stream>>>(X, W_in1, b_in1, W_rec1, W_out, b_out,
                                         hA, hB, bar, out);
}